// Round 2
// baseline (200.554 us; speedup 1.0000x reference)
//
#include <hip/hip_runtime.h>
#include <hip/hip_bf16.h>

typedef __attribute__((ext_vector_type(8))) short short8;
typedef __attribute__((ext_vector_type(4))) float f32x4;

#define MTOT 8192      // B*P
#define DDIM 256
#define BM   128       // rows per block (4 waves x 32 rows)
#define BN   64        // keys per inner iteration
#define SPLITS 8
#define KEYS_PER_SPLIT (MTOT / SPLITS)   // 1024
#define NIT (KEYS_PER_SPLIT / BN)        // 16

static constexpr float INV_T_F = 14.285714285714286f;   // 1/0.07
static constexpr float LOG2E   = 1.4426950408889634f;
static constexpr float LN2     = 0.6931471805599453f;
static constexpr float ALPHA   = INV_T_F * LOG2E;       // folded into q conversion

__device__ __forceinline__ unsigned short f2bf(float f) {
    union { float f; unsigned int u; } v; v.f = f;
    unsigned int r = v.u + 0x7fffu + ((v.u >> 16) & 1u);  // round-nearest-even
    return (unsigned short)(r >> 16);
}

// fp32 -> bf16 for both tensors; q gets ALPHA folded in so MFMA emits base-2 logits.
__global__ void convert_kernel(const float* __restrict__ q, const float* __restrict__ k,
                               ushort4* __restrict__ qb, ushort4* __restrict__ kb) {
    int i = blockIdx.x * blockDim.x + threadIdx.x;      // one float4 per thread
    const float4* q4 = (const float4*)q;
    const float4* k4 = (const float4*)k;
    float4 a = q4[i];
    ushort4 oa;
    oa.x = f2bf(a.x * ALPHA); oa.y = f2bf(a.y * ALPHA);
    oa.z = f2bf(a.z * ALPHA); oa.w = f2bf(a.w * ALPHA);
    qb[i] = oa;
    float4 b = k4[i];
    ushort4 ob;
    ob.x = f2bf(b.x); ob.y = f2bf(b.y); ob.z = f2bf(b.z); ob.w = f2bf(b.w);
    kb[i] = ob;
}

// Flash-LSE partials: grid (MTOT/BM, SPLITS). Each wave: 32 rows x all BN cols.
// 16x16x32 bf16 MFMA. A frag: row=lane&15, k=(lane>>4)*8+i. B frag: col=lane&15, same k.
// C/D: col=lane&15, row=(lane>>4)*4+reg  [m89-verified].
__global__ __launch_bounds__(256, 2) void flash_lse_kernel(
        const unsigned short* __restrict__ qb,
        const unsigned short* __restrict__ kb,
        float* __restrict__ part_m,
        float* __restrict__ part_s) {
    const int mblk  = blockIdx.x;
    const int split = blockIdx.y;
    const int wid   = threadIdx.x >> 6;
    const int lane  = threadIdx.x & 63;
    const int l16   = lane & 15;
    const int lg    = lane >> 4;
    const int row_base = mblk * BM + wid * 32;

    // Hoist Q fragments for this wave's 32 rows (2 row-tiles x 8 k-slices)
    short8 qf[2][8];
#pragma unroll
    for (int rt = 0; rt < 2; ++rt) {
#pragma unroll
        for (int kk = 0; kk < 8; ++kk) {
            const int row = row_base + rt * 16 + l16;
            qf[rt][kk] = *(const short8*)(qb + (size_t)row * DDIM + kk * 32 + lg * 8);
        }
    }

    float m_loc[2][4], s_loc[2][4];
#pragma unroll
    for (int rt = 0; rt < 2; ++rt)
#pragma unroll
        for (int j = 0; j < 4; ++j) { m_loc[rt][j] = -1e30f; s_loc[rt][j] = 0.f; }

    const int key0 = split * KEYS_PER_SPLIT;
    for (int it = 0; it < NIT; ++it) {
        const int kbase = key0 + it * BN;
        f32x4 acc[2][4];
#pragma unroll
        for (int rt = 0; rt < 2; ++rt)
#pragma unroll
            for (int ct = 0; ct < 4; ++ct)
                acc[rt][ct] = (f32x4){0.f, 0.f, 0.f, 0.f};

#pragma unroll
        for (int kk = 0; kk < 8; ++kk) {
            short8 bf[4];
#pragma unroll
            for (int ct = 0; ct < 4; ++ct) {
                const int col = kbase + ct * 16 + l16;
                bf[ct] = *(const short8*)(kb + (size_t)col * DDIM + kk * 32 + lg * 8);
            }
#pragma unroll
            for (int rt = 0; rt < 2; ++rt)
#pragma unroll
                for (int ct = 0; ct < 4; ++ct)
                    acc[rt][ct] = __builtin_amdgcn_mfma_f32_16x16x32_bf16(
                        qf[rt][kk], bf[ct], acc[rt][ct], 0, 0, 0);
        }

        // online logsumexp update (base-2 domain), per-lane local
#pragma unroll
        for (int rt = 0; rt < 2; ++rt) {
#pragma unroll
            for (int j = 0; j < 4; ++j) {
                const float x0 = acc[rt][0][j], x1 = acc[rt][1][j];
                const float x2 = acc[rt][2][j], x3 = acc[rt][3][j];
                const float mx = fmaxf(fmaxf(x0, x1), fmaxf(x2, x3));
                const float mo = m_loc[rt][j];
                const float mn = fmaxf(mo, mx);
                float s = s_loc[rt][j] * exp2f(mo - mn);
                s += exp2f(x0 - mn) + exp2f(x1 - mn) + exp2f(x2 - mn) + exp2f(x3 - mn);
                m_loc[rt][j] = mn;
                s_loc[rt][j] = s;
            }
        }
    }

    // reduce (m,s) across the 16 lanes holding different columns of each row
#pragma unroll
    for (int rt = 0; rt < 2; ++rt) {
#pragma unroll
        for (int j = 0; j < 4; ++j) {
            float m = m_loc[rt][j], s = s_loc[rt][j];
#pragma unroll
            for (int d = 1; d < 16; d <<= 1) {
                const float mo = __shfl_xor(m, d);
                const float so = __shfl_xor(s, d);
                const float mn = fmaxf(m, mo);
                s = s * exp2f(m - mn) + so * exp2f(mo - mn);
                m = mn;
            }
            if (l16 == 0) {
                const int row = row_base + rt * 16 + lg * 4 + j;
                part_m[split * MTOT + row] = m;
                part_s[split * MTOT + row] = s;
            }
        }
    }
}

// One wave per row: exact fp32 positive dot + split-merge -> loss.
__global__ void combine_kernel(const float* __restrict__ q, const float* __restrict__ k,
                               const float* __restrict__ part_m, const float* __restrict__ part_s,
                               float* __restrict__ out) {
    const int row  = (blockIdx.x * blockDim.x + threadIdx.x) >> 6;
    const int lane = threadIdx.x & 63;
    const float4 a = ((const float4*)(q + (size_t)row * DDIM))[lane];
    const float4 b = ((const float4*)(k + (size_t)row * DDIM))[lane];
    float dot = a.x * b.x + a.y * b.y + a.z * b.z + a.w * b.w;
#pragma unroll
    for (int d = 32; d >= 1; d >>= 1) dot += __shfl_xor(dot, d);
    if (lane == 0) {
        float m = -1e30f, s = 0.f;
#pragma unroll
        for (int p = 0; p < SPLITS; ++p) {
            const float mp = part_m[p * MTOT + row];
            const float sp = part_s[p * MTOT + row];
            const float mn = fmaxf(m, mp);
            s = s * exp2f(m - mn) + sp * exp2f(mp - mn);
            m = mn;
        }
        const float lse = (m + log2f(s)) * LN2;
        out[row] = lse - INV_T_F * dot;
    }
}

extern "C" void kernel_launch(void* const* d_in, const int* in_sizes, int n_in,
                              void* d_out, int out_size, void* d_ws, size_t ws_size,
                              hipStream_t stream) {
    const float* q = (const float*)d_in[0];
    const float* k = (const float*)d_in[1];
    float* out = (float*)d_out;

    char* ws = (char*)d_ws;
    unsigned short* qb = (unsigned short*)ws;                                   // 4 MB
    unsigned short* kb = (unsigned short*)(ws + (size_t)MTOT * DDIM * 2);       // 4 MB
    float* part_m = (float*)(ws + (size_t)MTOT * DDIM * 4);                     // 256 KB
    float* part_s = part_m + SPLITS * MTOT;                                     // 256 KB

    convert_kernel<<<(MTOT * DDIM / 4) / 256, 256, 0, stream>>>(q, k, (ushort4*)qb, (ushort4*)kb);
    dim3 grid(MTOT / BM, SPLITS);
    flash_lse_kernel<<<grid, 256, 0, stream>>>(qb, kb, part_m, part_s);
    combine_kernel<<<(MTOT * 64) / 256, 256, 0, stream>>>(q, k, part_m, part_s, out);
}

// Round 4
// 180.049 us; speedup vs baseline: 1.1139x; 1.1139x over previous
//
#include <hip/hip_runtime.h>
#include <hip/hip_bf16.h>

typedef __attribute__((ext_vector_type(8))) short short8;
typedef __attribute__((ext_vector_type(4))) float f32x4;

#define MTOT 8192      // B*P
#define DDIM 256
#define BM   128       // rows per block (4 waves x 32 rows each)
#define BN   64        // keys per inner iteration (4 col-tiles of 16)
#define SPLITS 16
#define KPS (MTOT / SPLITS)   // 512 keys per split
#define NIT (KPS / BN)        // 8 iters

static constexpr float INV_T_F = 14.285714285714286f;   // 1/0.07
static constexpr float LOG2E   = 1.4426950408889634f;
static constexpr float LN2     = 0.6931471805599453f;
static constexpr float ALPHA   = INV_T_F * LOG2E;       // folded into q fragments

__device__ __forceinline__ unsigned short f2bf(float f) {
    union { float f; unsigned int u; } v; v.f = f;
    unsigned int r = v.u + 0x7fffu + ((v.u >> 16) & 1u);  // round-nearest-even
    return (unsigned short)(r >> 16);
}

// K -> MFMA-B-fragment layout: kbT[g] for g = (cb*8 + kk)*64 + lane holds
// k[cb*16 + (lane&15)][kk*32 + (lane>>4)*8 .. +8] as bf16 short8.
// A wave's B-fragment load becomes ONE coalesced 1KB global_load_dwordx4.
__global__ void convert_kT_kernel(const float* __restrict__ k, short8* __restrict__ kbT) {
    const int g    = blockIdx.x * blockDim.x + threadIdx.x;
    const int lane = g & 63;
    const int kk   = (g >> 6) & 7;
    const int cb   = g >> 9;
    const int col  = cb * 16 + (lane & 15);
    const float* src = k + (size_t)col * DDIM + kk * 32 + (lane >> 4) * 8;
    const float4 a = *(const float4*)src;
    const float4 b = *(const float4*)(src + 4);
    short8 o;
    o[0] = (short)f2bf(a.x); o[1] = (short)f2bf(a.y);
    o[2] = (short)f2bf(a.z); o[3] = (short)f2bf(a.w);
    o[4] = (short)f2bf(b.x); o[5] = (short)f2bf(b.y);
    o[6] = (short)f2bf(b.z); o[7] = (short)f2bf(b.w);
    kbT[g] = o;
}

// Flash-LSE partials: grid (MTOT/BM, SPLITS). Each wave: 32 rows x BN cols/iter.
// 16x16x32 bf16 MFMA; C/D: col=lane&15, row=(lane>>4)*4+reg [m89-verified,
// round-2 pass confirms]. Q converted fp32->bf16 in-kernel (ALPHA folded).
__global__ __launch_bounds__(256, 4) void flash_lse_kernel(
        const float* __restrict__ q,
        const short8* __restrict__ kbT,
        float* __restrict__ part_m,
        float* __restrict__ part_s) {
    const int mblk  = blockIdx.x;
    const int split = blockIdx.y;
    const int wid   = threadIdx.x >> 6;
    const int lane  = threadIdx.x & 63;
    const int l16   = lane & 15;
    const int lg    = lane >> 4;
    const int row_base = mblk * BM + wid * 32;

    // Hoist Q fragments (convert on the fly, fold ALPHA)
    short8 qf[2][8];
#pragma unroll
    for (int rt = 0; rt < 2; ++rt) {
#pragma unroll
        for (int kk = 0; kk < 8; ++kk) {
            const int row = row_base + rt * 16 + l16;
            const float* src = q + (size_t)row * DDIM + kk * 32 + lg * 8;
            const float4 a = *(const float4*)src;
            const float4 b = *(const float4*)(src + 4);
            short8 o;
            o[0] = (short)f2bf(a.x * ALPHA); o[1] = (short)f2bf(a.y * ALPHA);
            o[2] = (short)f2bf(a.z * ALPHA); o[3] = (short)f2bf(a.w * ALPHA);
            o[4] = (short)f2bf(b.x * ALPHA); o[5] = (short)f2bf(b.y * ALPHA);
            o[6] = (short)f2bf(b.z * ALPHA); o[7] = (short)f2bf(b.w * ALPHA);
            qf[rt][kk] = o;
        }
    }

    float m_loc[2][4], s_loc[2][4];
#pragma unroll
    for (int rt = 0; rt < 2; ++rt)
#pragma unroll
        for (int j = 0; j < 4; ++j) { m_loc[rt][j] = -1e30f; s_loc[rt][j] = 0.f; }

    const int cb_base = split * (KPS / 16);
    for (int it = 0; it < NIT; ++it) {
        const int cb0 = cb_base + it * 4;
        f32x4 acc[2][4];
#pragma unroll
        for (int rt = 0; rt < 2; ++rt)
#pragma unroll
            for (int ct = 0; ct < 4; ++ct)
                acc[rt][ct] = (f32x4){0.f, 0.f, 0.f, 0.f};

#pragma unroll
        for (int kk = 0; kk < 8; ++kk) {
            short8 bf[4];
#pragma unroll
            for (int ct = 0; ct < 4; ++ct)
                bf[ct] = kbT[(size_t)((cb0 + ct) * 8 + kk) * 64 + lane];
#pragma unroll
            for (int rt = 0; rt < 2; ++rt)
#pragma unroll
                for (int ct = 0; ct < 4; ++ct)
                    acc[rt][ct] = __builtin_amdgcn_mfma_f32_16x16x32_bf16(
                        qf[rt][kk], bf[ct], acc[rt][ct], 0, 0, 0);
        }

        // online logsumexp update (base-2 domain), per-lane local
#pragma unroll
        for (int rt = 0; rt < 2; ++rt) {
#pragma unroll
            for (int j = 0; j < 4; ++j) {
                const float x0 = acc[rt][0][j], x1 = acc[rt][1][j];
                const float x2 = acc[rt][2][j], x3 = acc[rt][3][j];
                const float mx = fmaxf(fmaxf(x0, x1), fmaxf(x2, x3));
                const float mo = m_loc[rt][j];
                const float mn = fmaxf(mo, mx);
                float s = s_loc[rt][j] * exp2f(mo - mn);
                s += exp2f(x0 - mn) + exp2f(x1 - mn) + exp2f(x2 - mn) + exp2f(x3 - mn);
                m_loc[rt][j] = mn;
                s_loc[rt][j] = s;
            }
        }
    }

    // reduce (m,s) across the 16 lanes holding different columns of each row
#pragma unroll
    for (int rt = 0; rt < 2; ++rt) {
#pragma unroll
        for (int j = 0; j < 4; ++j) {
            float m = m_loc[rt][j], s = s_loc[rt][j];
#pragma unroll
            for (int d = 1; d < 16; d <<= 1) {
                const float mo = __shfl_xor(m, d);
                const float so = __shfl_xor(s, d);
                const float mn = fmaxf(m, mo);
                s = s * exp2f(m - mn) + so * exp2f(mo - mn);
                m = mn;
            }
            if (l16 == 0) {
                const int row = row_base + rt * 16 + lg * 4 + j;
                part_m[split * MTOT + row] = m;
                part_s[split * MTOT + row] = s;
            }
        }
    }
}

// One wave per row: exact fp32 positive dot + split-merge -> loss.
__global__ void combine_kernel(const float* __restrict__ q, const float* __restrict__ k,
                               const float* __restrict__ part_m, const float* __restrict__ part_s,
                               float* __restrict__ out) {
    const int row  = (blockIdx.x * blockDim.x + threadIdx.x) >> 6;
    const int lane = threadIdx.x & 63;
    const float4 a = ((const float4*)(q + (size_t)row * DDIM))[lane];
    const float4 b = ((const float4*)(k + (size_t)row * DDIM))[lane];
    float dot = a.x * b.x + a.y * b.y + a.z * b.z + a.w * b.w;
#pragma unroll
    for (int d = 32; d >= 1; d >>= 1) dot += __shfl_xor(dot, d);
    if (lane == 0) {
        float m = -1e30f, s = 0.f;
#pragma unroll
        for (int p = 0; p < SPLITS; ++p) {
            const float mp = part_m[p * MTOT + row];
            const float sp = part_s[p * MTOT + row];
            const float mn = fmaxf(m, mp);
            s = s * exp2f(m - mn) + sp * exp2f(mp - mn);
            m = mn;
        }
        const float lse = (m + log2f(s)) * LN2;
        out[row] = lse - INV_T_F * dot;
    }
}

extern "C" void kernel_launch(void* const* d_in, const int* in_sizes, int n_in,
                              void* d_out, int out_size, void* d_ws, size_t ws_size,
                              hipStream_t stream) {
    const float* q = (const float*)d_in[0];
    const float* k = (const float*)d_in[1];
    float* out = (float*)d_out;

    char* ws = (char*)d_ws;
    short8* kbT   = (short8*)ws;                                    // 4 MB
    float* part_m = (float*)(ws + (size_t)MTOT * DDIM * 2);         // 512 KB
    float* part_s = part_m + SPLITS * MTOT;                         // 512 KB

    convert_kT_kernel<<<(MTOT / 16 * 512) / 256, 256, 0, stream>>>(k, kbT);
    dim3 grid(MTOT / BM, SPLITS);
    flash_lse_kernel<<<grid, 256, 0, stream>>>(q, kbT, part_m, part_s);
    combine_kernel<<<(MTOT * 64) / 256, 256, 0, stream>>>(q, k, part_m, part_s, out);
}

// Round 6
// 153.392 us; speedup vs baseline: 1.3075x; 1.1738x over previous
//
#include <hip/hip_runtime.h>
#include <hip/hip_bf16.h>

typedef __attribute__((ext_vector_type(8))) short short8;
typedef __attribute__((ext_vector_type(4))) float f32x4;

#define MTOT 8192      // B*P
#define DDIM 256
#define BM   128       // rows per block (4 waves x 32 rows each)
#define SPLITS 16
#define KPS (MTOT / SPLITS)   // 512 keys per split
#define NIT (KPS / 64)        // 8 iters of 64 keys
#define NFRAG (MTOT / 16 * 8 * 64)   // 262144 short8 fragments per tensor

static constexpr float INV_T_F = 14.285714285714286f;   // 1/0.07
static constexpr float LOG2E   = 1.4426950408889634f;
static constexpr float LN2     = 0.6931471805599453f;
static constexpr float ALPHA   = INV_T_F * LOG2E;       // folded into q fragments

__device__ __forceinline__ unsigned short f2bf(float f) {
    union { float f; unsigned int u; } v; v.f = f;
    unsigned int r = v.u + 0x7fffu + ((v.u >> 16) & 1u);  // round-nearest-even
    return (unsigned short)(r >> 16);
}

// Both tensors -> MFMA fragment layout:
//   T[(tile*8 + kk)*64 + lane] = x[tile*16 + (lane&15)][kk*32 + (lane>>4)*8 .. +8]
// (bf16 short8; q scaled by ALPHA). A wave's fragment load is ONE coalesced
// 1KB global_load_dwordx4.
__global__ void convert_kernel(const float* __restrict__ q, const float* __restrict__ k,
                               short8* __restrict__ qbT, short8* __restrict__ kbT) {
    const int g    = blockIdx.x * blockDim.x + threadIdx.x;   // 0 .. 2*NFRAG-1
    const bool isQ = g >= NFRAG;
    const int gg   = isQ ? g - NFRAG : g;
    const int lane = gg & 63;
    const int kk   = (gg >> 6) & 7;
    const int tile = gg >> 9;
    const int row  = tile * 16 + (lane & 15);
    const float sc = isQ ? ALPHA : 1.0f;
    const float* src = (isQ ? q : k) + (size_t)row * DDIM + kk * 32 + (lane >> 4) * 8;
    const float4 a = *(const float4*)src;
    const float4 b = *(const float4*)(src + 4);
    short8 o;
    o[0] = (short)f2bf(a.x * sc); o[1] = (short)f2bf(a.y * sc);
    o[2] = (short)f2bf(a.z * sc); o[3] = (short)f2bf(a.w * sc);
    o[4] = (short)f2bf(b.x * sc); o[5] = (short)f2bf(b.y * sc);
    o[6] = (short)f2bf(b.z * sc); o[7] = (short)f2bf(b.w * sc);
    (isQ ? qbT : kbT)[gg] = o;
}

// Flash-LSE partials: grid (MTOT/BM, SPLITS). Each wave: 32 rows x 64 keys/iter.
// 16x16x32 bf16 MFMA; C/D: col=lane&15, row=(lane>>4)*4+reg [verified r2/r4 pass].
// Budget: qf 64 + acc 32 + bf 32 + m/s 16 + addr ~15 ≈ 160 VGPR -> bounds (256,3).
__global__ __launch_bounds__(256, 3) void flash_lse_kernel(
        const short8* __restrict__ qbT,
        const short8* __restrict__ kbT,
        float* __restrict__ part_m,
        float* __restrict__ part_s) {
    const int mblk  = blockIdx.x;
    const int split = blockIdx.y;
    const int wid   = threadIdx.x >> 6;
    const int lane  = threadIdx.x & 63;
    const int l16   = lane & 15;
    const int lg    = lane >> 4;
    const int rt16  = mblk * 8 + wid * 2;   // first of this wave's two row-tiles

    // Hoist Q fragments: 16 coalesced loads, held in registers for the whole kernel.
    short8 qf[2][8];
#pragma unroll
    for (int rt = 0; rt < 2; ++rt)
#pragma unroll
        for (int kk = 0; kk < 8; ++kk)
            qf[rt][kk] = qbT[(size_t)((rt16 + rt) * 8 + kk) * 64 + lane];

    float m_loc[2][4], s_loc[2][4];
#pragma unroll
    for (int rt = 0; rt < 2; ++rt)
#pragma unroll
        for (int j = 0; j < 4; ++j) { m_loc[rt][j] = -1e30f; s_loc[rt][j] = 0.f; }

    const int cb_base = split * (KPS / 16);
    for (int it = 0; it < NIT; ++it) {
        const int cb0 = cb_base + it * 4;
        f32x4 acc[2][4];
#pragma unroll
        for (int rt = 0; rt < 2; ++rt)
#pragma unroll
            for (int ct = 0; ct < 4; ++ct)
                acc[rt][ct] = (f32x4){0.f, 0.f, 0.f, 0.f};

        // 2-deep software pipeline on B fragments (static indices after unroll)
        short8 bf[2][4];
#pragma unroll
        for (int ct = 0; ct < 4; ++ct)
            bf[0][ct] = kbT[(size_t)((cb0 + ct) * 8 + 0) * 64 + lane];

#pragma unroll
        for (int kk = 0; kk < 8; ++kk) {
            if (kk < 7) {
#pragma unroll
                for (int ct = 0; ct < 4; ++ct)
                    bf[(kk + 1) & 1][ct] = kbT[(size_t)((cb0 + ct) * 8 + kk + 1) * 64 + lane];
            }
#pragma unroll
            for (int rt = 0; rt < 2; ++rt)
#pragma unroll
                for (int ct = 0; ct < 4; ++ct)
                    acc[rt][ct] = __builtin_amdgcn_mfma_f32_16x16x32_bf16(
                        qf[rt][kk], bf[kk & 1][ct], acc[rt][ct], 0, 0, 0);
        }

        // online logsumexp update (base-2 domain), per-lane local
#pragma unroll
        for (int rt = 0; rt < 2; ++rt) {
#pragma unroll
            for (int j = 0; j < 4; ++j) {
                const float x0 = acc[rt][0][j], x1 = acc[rt][1][j];
                const float x2 = acc[rt][2][j], x3 = acc[rt][3][j];
                const float mo = m_loc[rt][j];
                const float mn = fmaxf(fmaxf(fmaxf(x0, x1), fmaxf(x2, x3)), mo);
                float s = s_loc[rt][j] * exp2f(mo - mn);
                s += exp2f(x0 - mn) + exp2f(x1 - mn) + exp2f(x2 - mn) + exp2f(x3 - mn);
                m_loc[rt][j] = mn;
                s_loc[rt][j] = s;
            }
        }
    }

    // reduce (m,s) across the 16 lanes holding different columns of each row
#pragma unroll
    for (int rt = 0; rt < 2; ++rt) {
#pragma unroll
        for (int j = 0; j < 4; ++j) {
            float m = m_loc[rt][j], s = s_loc[rt][j];
#pragma unroll
            for (int d = 1; d < 16; d <<= 1) {
                const float mo = __shfl_xor(m, d);
                const float so = __shfl_xor(s, d);
                const float mn = fmaxf(m, mo);
                s = s * exp2f(m - mn) + so * exp2f(mo - mn);
                m = mn;
            }
            if (l16 == 0) {
                const int row = rt16 * 16 + rt * 16 + lg * 4 + j;
                part_m[split * MTOT + row] = m;
                part_s[split * MTOT + row] = s;
            }
        }
    }
}

// One wave per row: exact fp32 positive dot + split-merge -> loss.
__global__ void combine_kernel(const float* __restrict__ q, const float* __restrict__ k,
                               const float* __restrict__ part_m, const float* __restrict__ part_s,
                               float* __restrict__ out) {
    const int row  = (blockIdx.x * blockDim.x + threadIdx.x) >> 6;
    const int lane = threadIdx.x & 63;
    const float4 a = ((const float4*)(q + (size_t)row * DDIM))[lane];
    const float4 b = ((const float4*)(k + (size_t)row * DDIM))[lane];
    float dot = a.x * b.x + a.y * b.y + a.z * b.z + a.w * b.w;
#pragma unroll
    for (int d = 32; d >= 1; d >>= 1) dot += __shfl_xor(dot, d);
    if (lane == 0) {
        float m = -1e30f, s = 0.f;
#pragma unroll
        for (int p = 0; p < SPLITS; ++p) {
            const float mp = part_m[p * MTOT + row];
            const float sp = part_s[p * MTOT + row];
            const float mn = fmaxf(m, mp);
            s = s * exp2f(m - mn) + sp * exp2f(mp - mn);
            m = mn;
        }
        const float lse = (m + log2f(s)) * LN2;
        out[row] = lse - INV_T_F * dot;
    }
}

extern "C" void kernel_launch(void* const* d_in, const int* in_sizes, int n_in,
                              void* d_out, int out_size, void* d_ws, size_t ws_size,
                              hipStream_t stream) {
    const float* q = (const float*)d_in[0];
    const float* k = (const float*)d_in[1];
    float* out = (float*)d_out;

    char* ws = (char*)d_ws;
    short8* qbT   = (short8*)ws;                                    // 4 MB
    short8* kbT   = (short8*)(ws + (size_t)NFRAG * 16);             // 4 MB
    float* part_m = (float*)(ws + (size_t)NFRAG * 32);              // 512 KB
    float* part_s = part_m + SPLITS * MTOT;                         // 512 KB

    convert_kernel<<<(2 * NFRAG) / 256, 256, 0, stream>>>(q, k, qbT, kbT);
    dim3 grid(MTOT / BM, SPLITS);
    flash_lse_kernel<<<grid, 256, 0, stream>>>(qbT, kbT, part_m, part_s);
    combine_kernel<<<(MTOT * 64) / 256, 256, 0, stream>>>(q, k, part_m, part_s, out);
}

// Round 8
// 116.875 us; speedup vs baseline: 1.7160x; 1.3125x over previous
//
#include <hip/hip_runtime.h>
#include <hip/hip_bf16.h>

typedef __attribute__((ext_vector_type(8))) short short8;
typedef __attribute__((ext_vector_type(4))) float f32x4;

#define MTOT 8192      // B*P
#define DDIM 256
#define BM   128       // rows per block (4 waves x 32 rows each)
#define SPLITS 8
#define KPS (MTOT / SPLITS)          // 1024 keys per split
#define NIT (KPS / 64)               // 16 iters of 64 keys
#define NFRAG (MTOT * 32)            // 262144 short8 fragments per tensor

static constexpr float INV_T_F = 14.285714285714286f;   // 1/0.07
static constexpr float LOG2E   = 1.4426950408889634f;
static constexpr float LN2     = 0.6931471805599453f;
static constexpr float ALPHA   = INV_T_F * LOG2E;       // folded into q fragments

__device__ __forceinline__ unsigned short f2bf(float f) {
    union { float f; unsigned int u; } v; v.f = f;
    unsigned int r = v.u + 0x7fffu + ((v.u >> 16) & 1u);  // round-nearest-even
    return (unsigned short)(r >> 16);
}

// Fragment layout (both tensors): frag[(tile*8 + kk)*64 + lane] holds
// x[tile*16 + (lane&15)][kk*32 + (lane>>4)*8 .. +8] as bf16 short8 (q scaled
// by ALPHA). This kernel reads COALESCED (consecutive threads = consecutive
// 32B source chunks) and scatters 16B writes (posted stores, L2 absorbs).
__global__ void convert_kernel(const float* __restrict__ q, const float* __restrict__ k,
                               short8* __restrict__ qbT, short8* __restrict__ kbT) {
    const int g    = blockIdx.x * blockDim.x + threadIdx.x;   // 0 .. 2*NFRAG-1
    const bool isQ = g >= NFRAG;
    const int gg   = isQ ? g - NFRAG : g;
    const int row  = gg >> 5;        // source row
    const int c8   = gg & 31;        // 8-dim chunk within row
    const float sc = isQ ? ALPHA : 1.0f;
    const float4* src = (const float4*)(isQ ? q : k);
    const float4 a = src[(size_t)gg * 2];
    const float4 b = src[(size_t)gg * 2 + 1];
    short8 o;
    o[0] = (short)f2bf(a.x * sc); o[1] = (short)f2bf(a.y * sc);
    o[2] = (short)f2bf(a.z * sc); o[3] = (short)f2bf(a.w * sc);
    o[4] = (short)f2bf(b.x * sc); o[5] = (short)f2bf(b.y * sc);
    o[6] = (short)f2bf(b.z * sc); o[7] = (short)f2bf(b.w * sc);
    // dest fragment: tile=row>>4, kk=c8>>2, lg=c8&3, l16=row&15
    const int dst = ((row >> 4) * 8 + (c8 >> 2)) * 64 + (c8 & 3) * 16 + (row & 15);
    (isQ ? qbT : kbT)[dst] = o;
}

// Issue 8 x global_load_lds width=16: one wave stages a contiguous 8KB chunk.
// LDS dest is wave-uniform base + lane*16 (HW rule); global src is per-lane.
__device__ __forceinline__ void stage_chunk(const short8* __restrict__ src_base,
                                            short8* lds_base, int lane) {
#pragma unroll
    for (int i = 0; i < 8; ++i) {
        const short8* g = src_base + i * 64 + lane;
        short8* l = lds_base + i * 64;
        __builtin_amdgcn_global_load_lds(
            (const __attribute__((address_space(1))) unsigned int*)g,
            (__attribute__((address_space(3))) unsigned int*)l,
            16, 0, 0);
    }
}

// Flash-LSE partials: grid (MTOT/BM, SPLITS) = 512 blocks = 2/CU (LDS-bound).
// K tile (64 keys = 32KB) double-buffered in LDS, staged cooperatively by the
// 4 waves via global_load_lds; fragments are lane-linear -> conflict-free
// ds_read_b128. Q fragments held in registers for the whole kernel.
// C/D map: col=lane&15, row=(lane>>4)*4+reg [verified r2/r4/r6 pass].
__global__ __launch_bounds__(256, 2) void flash_lse_kernel(
        const short8* __restrict__ qbT,
        const short8* __restrict__ kbT,
        float* __restrict__ part_m,
        float* __restrict__ part_s) {
    __shared__ short8 smem[2][2048];   // 2 x 32KB

    const int mblk  = blockIdx.x;
    const int split = blockIdx.y;
    const int wid   = threadIdx.x >> 6;
    const int lane  = threadIdx.x & 63;
    const int l16   = lane & 15;
    const int lg    = lane >> 4;
    const int rt16  = mblk * 8 + wid * 2;   // first of this wave's two row-tiles

    // Hoist Q fragments: 16 coalesced 1KB loads, live for the whole kernel.
    short8 qf[2][8];
#pragma unroll
    for (int rt = 0; rt < 2; ++rt)
#pragma unroll
        for (int kk = 0; kk < 8; ++kk)
            qf[rt][kk] = qbT[(size_t)((rt16 + rt) * 8 + kk) * 64 + lane];

    float m_loc[2][4], s_loc[2][4];
#pragma unroll
    for (int rt = 0; rt < 2; ++rt)
#pragma unroll
        for (int j = 0; j < 4; ++j) { m_loc[rt][j] = -1e30f; s_loc[rt][j] = 0.f; }

    // tile it covers col-tiles cb0(it) = split*64 + it*4; global short8 base
    // = cb0*512; each tile is 2048 contiguous short8 (32KB).
    const size_t tile_base0 = (size_t)(split * 64) * 512;

    // prologue: stage tile 0 into buf 0
    stage_chunk(kbT + tile_base0 + wid * 512, &smem[0][wid * 512], lane);
    __syncthreads();   // drains vmcnt -> tile 0 resident

    for (int it = 0; it < NIT; ++it) {
        const int cur = it & 1;
        if (it + 1 < NIT) {
            const size_t nbase = tile_base0 + (size_t)(it + 1) * 2048;
            stage_chunk(kbT + nbase + wid * 512, &smem[cur ^ 1][wid * 512], lane);
        }

        f32x4 acc[2][4];
#pragma unroll
        for (int rt = 0; rt < 2; ++rt)
#pragma unroll
            for (int ct = 0; ct < 4; ++ct)
                acc[rt][ct] = (f32x4){0.f, 0.f, 0.f, 0.f};

        const short8* sb = smem[cur];
#pragma unroll
        for (int kk = 0; kk < 8; ++kk) {
            short8 bf[4];
#pragma unroll
            for (int ct = 0; ct < 4; ++ct)
                bf[ct] = sb[(ct * 8 + kk) * 64 + lane];
#pragma unroll
            for (int rt = 0; rt < 2; ++rt)
#pragma unroll
                for (int ct = 0; ct < 4; ++ct)
                    acc[rt][ct] = __builtin_amdgcn_mfma_f32_16x16x32_bf16(
                        qf[rt][kk], bf[ct], acc[rt][ct], 0, 0, 0);
        }

        // online logsumexp update (base-2 domain), per-lane partial over cols
#pragma unroll
        for (int rt = 0; rt < 2; ++rt) {
#pragma unroll
            for (int j = 0; j < 4; ++j) {
                const float x0 = acc[rt][0][j], x1 = acc[rt][1][j];
                const float x2 = acc[rt][2][j], x3 = acc[rt][3][j];
                const float mo = m_loc[rt][j];
                const float mn = fmaxf(fmaxf(fmaxf(x0, x1), fmaxf(x2, x3)), mo);
                float s = s_loc[rt][j] * exp2f(mo - mn);
                s += exp2f(x0 - mn) + exp2f(x1 - mn) + exp2f(x2 - mn) + exp2f(x3 - mn);
                m_loc[rt][j] = mn;
                s_loc[rt][j] = s;
            }
        }

        __syncthreads();   // next tile landed (vmcnt drain) + all waves done with cur
    }

    // reduce (m,s) across the 16 lanes holding different columns of each row
#pragma unroll
    for (int rt = 0; rt < 2; ++rt) {
#pragma unroll
        for (int j = 0; j < 4; ++j) {
            float m = m_loc[rt][j], s = s_loc[rt][j];
#pragma unroll
            for (int d = 1; d < 16; d <<= 1) {
                const float mo = __shfl_xor(m, d);
                const float so = __shfl_xor(s, d);
                const float mn = fmaxf(m, mo);
                s = s * exp2f(m - mn) + so * exp2f(mo - mn);
                m = mn;
            }
            if (l16 == 0) {
                const int row = (rt16 + rt) * 16 + lg * 4 + j;
                part_m[split * MTOT + row] = m;
                part_s[split * MTOT + row] = s;
            }
        }
    }
}

// One wave per row: exact fp32 positive dot + parallel split-merge -> loss.
__global__ void combine_kernel(const float* __restrict__ q, const float* __restrict__ k,
                               const float* __restrict__ part_m, const float* __restrict__ part_s,
                               float* __restrict__ out) {
    const int row  = (blockIdx.x * blockDim.x + threadIdx.x) >> 6;
    const int lane = threadIdx.x & 63;
    const float4 a = ((const float4*)(q + (size_t)row * DDIM))[lane];
    const float4 b = ((const float4*)(k + (size_t)row * DDIM))[lane];
    float dot = a.x * b.x + a.y * b.y + a.z * b.z + a.w * b.w;
#pragma unroll
    for (int d = 32; d >= 1; d >>= 1) dot += __shfl_xor(dot, d);

    // lanes 0..7 each load one split's (m,s); 3-level xor merge within group
    float m = -1e30f, s = 0.f;
    if (lane < SPLITS) {
        m = part_m[lane * MTOT + row];
        s = part_s[lane * MTOT + row];
    }
#pragma unroll
    for (int d = 1; d < SPLITS; d <<= 1) {
        const float mo = __shfl_xor(m, d);
        const float so = __shfl_xor(s, d);
        const float mn = fmaxf(m, mo);
        s = s * exp2f(m - mn) + so * exp2f(mo - mn);
        m = mn;
    }
    if (lane == 0) {
        const float lse = (m + log2f(s)) * LN2;
        out[row] = lse - INV_T_F * dot;
    }
}

extern "C" void kernel_launch(void* const* d_in, const int* in_sizes, int n_in,
                              void* d_out, int out_size, void* d_ws, size_t ws_size,
                              hipStream_t stream) {
    const float* q = (const float*)d_in[0];
    const float* k = (const float*)d_in[1];
    float* out = (float*)d_out;

    char* ws = (char*)d_ws;
    short8* qbT   = (short8*)ws;                                    // 4 MB
    short8* kbT   = (short8*)(ws + (size_t)NFRAG * 16);             // 4 MB
    float* part_m = (float*)(ws + (size_t)NFRAG * 32);              // 256 KB
    float* part_s = part_m + SPLITS * MTOT;                         // 256 KB

    convert_kernel<<<(2 * NFRAG) / 256, 256, 0, stream>>>(q, k, qbT, kbT);
    dim3 grid(MTOT / BM, SPLITS);
    flash_lse_kernel<<<grid, 256, 0, stream>>>(qbT, kbT, part_m, part_s);
    combine_kernel<<<(MTOT * 64) / 256, 256, 0, stream>>>(q, k, part_m, part_s, out);
}

// Round 11
// 109.858 us; speedup vs baseline: 1.8256x; 1.0639x over previous
//
#include <hip/hip_runtime.h>
#include <hip/hip_bf16.h>

typedef __attribute__((ext_vector_type(8))) short short8;
typedef __attribute__((ext_vector_type(4))) float f32x4;

#define MTOT 8192      // B*P
#define DDIM 256
#define BM   256       // rows per block (8 waves x 32 rows each)
#define SPLITS 16
#define KPS (MTOT / SPLITS)          // 512 keys per split
#define NIT (KPS / 64)               // 8 iters of 64 keys
#define NFRAG (MTOT * 32)            // 262144 short8 fragments per tensor

static constexpr float INV_T_F = 14.285714285714286f;   // 1/0.07
static constexpr float LOG2E   = 1.4426950408889634f;
static constexpr float LN2     = 0.6931471805599453f;
static constexpr float ALPHA   = INV_T_F * LOG2E;       // folded into q fragments

__device__ __forceinline__ unsigned short f2bf(float f) {
    union { float f; unsigned int u; } v; v.f = f;
    unsigned int r = v.u + 0x7fffu + ((v.u >> 16) & 1u);  // round-nearest-even
    return (unsigned short)(r >> 16);
}
// raw v_exp_f32: args are always <= 0 here; -huge flushes to 0 (correct)
#define EXP2R(x) __builtin_amdgcn_exp2f(x)

// Fragment layout (both tensors): frag[(tile*8 + kk)*64 + lane] holds
// x[tile*16 + (lane&15)][kk*32 + (lane>>4)*8 .. +8] as bf16 short8 (q scaled
// by ALPHA). Each thread handles one (row, 8-dim-chunk) for BOTH q and k
// (coalesced 2x64B reads), and the 32 threads of a row cooperatively produce
// the EXACT fp32 positive dot q[row].k[row] (written to dots[]).
__global__ void convert_kernel(const float* __restrict__ q, const float* __restrict__ k,
                               short8* __restrict__ qbT, short8* __restrict__ kbT,
                               float* __restrict__ dots) {
    const int g   = blockIdx.x * blockDim.x + threadIdx.x;   // 0 .. NFRAG-1
    const int row = g >> 5;        // source row
    const int c8  = g & 31;        // 8-dim chunk within row
    const float4* q4 = (const float4*)q;
    const float4* k4 = (const float4*)k;
    const float4 qa = q4[(size_t)g * 2], qb = q4[(size_t)g * 2 + 1];
    const float4 ka = k4[(size_t)g * 2], kb = k4[(size_t)g * 2 + 1];

    short8 oq, ok;
    oq[0] = (short)f2bf(qa.x * ALPHA); oq[1] = (short)f2bf(qa.y * ALPHA);
    oq[2] = (short)f2bf(qa.z * ALPHA); oq[3] = (short)f2bf(qa.w * ALPHA);
    oq[4] = (short)f2bf(qb.x * ALPHA); oq[5] = (short)f2bf(qb.y * ALPHA);
    oq[6] = (short)f2bf(qb.z * ALPHA); oq[7] = (short)f2bf(qb.w * ALPHA);
    ok[0] = (short)f2bf(ka.x); ok[1] = (short)f2bf(ka.y);
    ok[2] = (short)f2bf(ka.z); ok[3] = (short)f2bf(ka.w);
    ok[4] = (short)f2bf(kb.x); ok[5] = (short)f2bf(kb.y);
    ok[6] = (short)f2bf(kb.z); ok[7] = (short)f2bf(kb.w);
    const int dst = ((row >> 4) * 8 + (c8 >> 2)) * 64 + (c8 & 3) * 16 + (row & 15);
    qbT[dst] = oq;
    kbT[dst] = ok;

    // exact fp32 positive dot: chunk dot + 32-lane xor reduce (row = 32 lanes)
    float d = qa.x * ka.x + qa.y * ka.y + qa.z * ka.z + qa.w * ka.w
            + qb.x * kb.x + qb.y * kb.y + qb.z * kb.z + qb.w * kb.w;
#pragma unroll
    for (int s = 1; s < 32; s <<= 1) d += __shfl_xor(d, s);
    if (c8 == 0) dots[row] = d;
}

// One wave stages a contiguous 4KB chunk (256 short8) via 4 global_load_lds
// width=16. LDS dest is wave-uniform base + lane*16 (HW rule).
__device__ __forceinline__ void stage_chunk(const short8* __restrict__ src_base,
                                            short8* lds_base, int lane) {
#pragma unroll
    for (int i = 0; i < 4; ++i) {
        const short8* g = src_base + i * 64 + lane;
        short8* l = lds_base + i * 64;
        __builtin_amdgcn_global_load_lds(
            (const __attribute__((address_space(1))) unsigned int*)g,
            (__attribute__((address_space(3))) unsigned int*)l,
            16, 0, 0);
    }
}

// Flash-LSE partials: grid (MTOT/BM, SPLITS) = (32,16) = 512 blocks = 2/CU,
// 8 waves/block -> 4 waves/SIMD. K tile (64 keys = 32KB) double-buffered in
// LDS (2x32KB), staged cooperatively by 8 waves; fragments lane-linear ->
// conflict-free ds_read_b128. Q fragments in registers for the whole kernel.
// C/D map: col=lane&15, row=(lane>>4)*4+reg [verified r2/r4/r6/r8 pass].
__global__ __launch_bounds__(512, 4) void flash_lse_kernel(
        const short8* __restrict__ qbT,
        const short8* __restrict__ kbT,
        float* __restrict__ part_m,
        float* __restrict__ part_s) {
    __shared__ short8 smem[2][2048];   // 2 x 32KB

    const int mblk  = blockIdx.x;
    const int split = blockIdx.y;
    const int wid   = threadIdx.x >> 6;
    const int lane  = threadIdx.x & 63;
    const int l16   = lane & 15;
    const int lg    = lane >> 4;
    const int rt16  = mblk * 16 + wid * 2;   // first of this wave's two row-tiles

    // Hoist Q fragments: 16 coalesced 1KB loads, live for the whole kernel.
    short8 qf[2][8];
#pragma unroll
    for (int rt = 0; rt < 2; ++rt)
#pragma unroll
        for (int kk = 0; kk < 8; ++kk)
            qf[rt][kk] = qbT[(size_t)((rt16 + rt) * 8 + kk) * 64 + lane];

    float m_loc[2][4], s_loc[2][4];
#pragma unroll
    for (int rt = 0; rt < 2; ++rt)
#pragma unroll
        for (int j = 0; j < 4; ++j) { m_loc[rt][j] = -1e30f; s_loc[rt][j] = 0.f; }

    // split covers 32 col-tiles starting at split*32; iter it covers 4 of them
    // (64 keys = 2048 contiguous short8 = 32KB).
    const size_t tile_base0 = (size_t)(split * 32) * 512;

    // prologue: stage tile 0 into buf 0 (each of 8 waves stages 4KB)
    stage_chunk(kbT + tile_base0 + wid * 256, &smem[0][wid * 256], lane);
    __syncthreads();   // drains vmcnt -> tile 0 resident

    for (int it = 0; it < NIT; ++it) {
        const int cur = it & 1;
        if (it + 1 < NIT) {
            const size_t nbase = tile_base0 + (size_t)(it + 1) * 2048;
            stage_chunk(kbT + nbase + wid * 256, &smem[cur ^ 1][wid * 256], lane);
        }

        f32x4 acc[2][4];
#pragma unroll
        for (int rt = 0; rt < 2; ++rt)
#pragma unroll
            for (int ct = 0; ct < 4; ++ct)
                acc[rt][ct] = (f32x4){0.f, 0.f, 0.f, 0.f};

        const short8* sb = smem[cur];
#pragma unroll
        for (int kk = 0; kk < 8; ++kk) {
            short8 bf[4];
#pragma unroll
            for (int ct = 0; ct < 4; ++ct)
                bf[ct] = sb[(ct * 8 + kk) * 64 + lane];
#pragma unroll
            for (int rt = 0; rt < 2; ++rt)
#pragma unroll
                for (int ct = 0; ct < 4; ++ct)
                    acc[rt][ct] = __builtin_amdgcn_mfma_f32_16x16x32_bf16(
                        qf[rt][kk], bf[ct], acc[rt][ct], 0, 0, 0);
        }

        // online logsumexp update (base-2 domain), per-lane partial over cols
#pragma unroll
        for (int rt = 0; rt < 2; ++rt) {
#pragma unroll
            for (int j = 0; j < 4; ++j) {
                const float x0 = acc[rt][0][j], x1 = acc[rt][1][j];
                const float x2 = acc[rt][2][j], x3 = acc[rt][3][j];
                const float mo = m_loc[rt][j];
                const float mn = fmaxf(fmaxf(fmaxf(x0, x1), fmaxf(x2, x3)), mo);
                float s = s_loc[rt][j] * EXP2R(mo - mn);
                s += EXP2R(x0 - mn) + EXP2R(x1 - mn) + EXP2R(x2 - mn) + EXP2R(x3 - mn);
                m_loc[rt][j] = mn;
                s_loc[rt][j] = s;
            }
        }

        __syncthreads();   // next tile landed (vmcnt drain) + all waves done with cur
    }

    // reduce (m,s) across the 16 lanes holding different columns of each row
#pragma unroll
    for (int rt = 0; rt < 2; ++rt) {
#pragma unroll
        for (int j = 0; j < 4; ++j) {
            float m = m_loc[rt][j], s = s_loc[rt][j];
#pragma unroll
            for (int d = 1; d < 16; d <<= 1) {
                const float mo = __shfl_xor(m, d);
                const float so = __shfl_xor(s, d);
                const float mn = fmaxf(m, mo);
                s = s * EXP2R(m - mn) + so * EXP2R(mo - mn);
                m = mn;
            }
            if (l16 == 0) {
                const int row = (rt16 + rt) * 16 + lg * 4 + j;
                part_m[split * MTOT + row] = m;
                part_s[split * MTOT + row] = s;
            }
        }
    }
}

// 16 lanes per row: merge the 16 split-partials + exact positive dot -> loss.
__global__ void combine_kernel(const float* __restrict__ dots,
                               const float* __restrict__ part_m,
                               const float* __restrict__ part_s,
                               float* __restrict__ out) {
    const int tid  = blockIdx.x * blockDim.x + threadIdx.x;
    const int row  = tid >> 4;
    const int l16  = tid & 15;
    float m = part_m[l16 * MTOT + row];
    float s = part_s[l16 * MTOT + row];
#pragma unroll
    for (int d = 1; d < 16; d <<= 1) {
        const float mo = __shfl_xor(m, d);
        const float so = __shfl_xor(s, d);
        const float mn = fmaxf(m, mo);
        s = s * EXP2R(m - mn) + so * EXP2R(mo - mn);
        m = mn;
    }
    if (l16 == 0) {
        out[row] = (m + __log2f(s)) * LN2 - INV_T_F * dots[row];
    }
}

extern "C" void kernel_launch(void* const* d_in, const int* in_sizes, int n_in,
                              void* d_out, int out_size, void* d_ws, size_t ws_size,
                              hipStream_t stream) {
    const float* q = (const float*)d_in[0];
    const float* k = (const float*)d_in[1];
    float* out = (float*)d_out;

    char* ws = (char*)d_ws;
    short8* qbT   = (short8*)ws;                                    // 4 MB
    short8* kbT   = (short8*)(ws + (size_t)NFRAG * 16);             // 4 MB
    float* part_m = (float*)(ws + (size_t)NFRAG * 32);              // 512 KB
    float* part_s = part_m + SPLITS * MTOT;                         // 512 KB
    float* dots   = part_s + SPLITS * MTOT;                         // 32 KB

    convert_kernel<<<NFRAG / 256, 256, 0, stream>>>(q, k, qbT, kbT, dots);
    dim3 grid(MTOT / BM, SPLITS);
    flash_lse_kernel<<<grid, 512, 0, stream>>>(qbT, kbT, part_m, part_s);
    combine_kernel<<<(MTOT * 16) / 256, 256, 0, stream>>>(dots, part_m, part_s, out);
}

// Round 12
// 106.046 us; speedup vs baseline: 1.8912x; 1.0359x over previous
//
#include <hip/hip_runtime.h>
#include <hip/hip_bf16.h>

typedef __attribute__((ext_vector_type(8))) short short8;
typedef __attribute__((ext_vector_type(4))) float f32x4;

#define MTOT 8192      // B*P
#define DDIM 256
#define BM   128       // rows per block (4 waves x 32 rows each)
#define BN   32        // keys per LDS tile (2 col-tiles of 16) = 16KB
#define SPLITS 16
#define KPS (MTOT / SPLITS)          // 512 keys per split
#define NIT (KPS / BN)               // 16 iters
#define NFRAG (MTOT * 32)            // 262144 short8 fragments per tensor

static constexpr float INV_T_F = 14.285714285714286f;   // 1/0.07
static constexpr float LOG2E   = 1.4426950408889634f;
static constexpr float LN2     = 0.6931471805599453f;
static constexpr float ALPHA   = INV_T_F * LOG2E;       // folded into q fragments

__device__ __forceinline__ unsigned short f2bf(float f) {
    union { float f; unsigned int u; } v; v.f = f;
    unsigned int r = v.u + 0x7fffu + ((v.u >> 16) & 1u);  // round-nearest-even
    return (unsigned short)(r >> 16);
}
// raw v_exp_f32: args are always <= 0 here; -huge flushes to 0 (correct)
#define EXP2R(x) __builtin_amdgcn_exp2f(x)

// Fragment layout (both tensors): frag[(tile*8 + kk)*64 + lane] holds
// x[tile*16 + (lane&15)][kk*32 + (lane>>4)*8 .. +8] as bf16 short8 (q scaled
// by ALPHA). Each thread handles one (row, 8-dim-chunk) for BOTH q and k
// (coalesced 2x64B reads); 32 threads of a row produce the EXACT fp32
// positive dot via 5-level shuffle (written to dots[]).
__global__ void convert_kernel(const float* __restrict__ q, const float* __restrict__ k,
                               short8* __restrict__ qbT, short8* __restrict__ kbT,
                               float* __restrict__ dots) {
    const int g   = blockIdx.x * blockDim.x + threadIdx.x;   // 0 .. NFRAG-1
    const int row = g >> 5;        // source row
    const int c8  = g & 31;        // 8-dim chunk within row
    const float4* q4 = (const float4*)q;
    const float4* k4 = (const float4*)k;
    const float4 qa = q4[(size_t)g * 2], qb = q4[(size_t)g * 2 + 1];
    const float4 ka = k4[(size_t)g * 2], kb = k4[(size_t)g * 2 + 1];

    short8 oq, ok;
    oq[0] = (short)f2bf(qa.x * ALPHA); oq[1] = (short)f2bf(qa.y * ALPHA);
    oq[2] = (short)f2bf(qa.z * ALPHA); oq[3] = (short)f2bf(qa.w * ALPHA);
    oq[4] = (short)f2bf(qb.x * ALPHA); oq[5] = (short)f2bf(qb.y * ALPHA);
    oq[6] = (short)f2bf(qb.z * ALPHA); oq[7] = (short)f2bf(qb.w * ALPHA);
    ok[0] = (short)f2bf(ka.x); ok[1] = (short)f2bf(ka.y);
    ok[2] = (short)f2bf(ka.z); ok[3] = (short)f2bf(ka.w);
    ok[4] = (short)f2bf(kb.x); ok[5] = (short)f2bf(kb.y);
    ok[6] = (short)f2bf(kb.z); ok[7] = (short)f2bf(kb.w);
    const int dst = ((row >> 4) * 8 + (c8 >> 2)) * 64 + (c8 & 3) * 16 + (row & 15);
    qbT[dst] = oq;
    kbT[dst] = ok;

    float d = qa.x * ka.x + qa.y * ka.y + qa.z * ka.z + qa.w * ka.w
            + qb.x * kb.x + qb.y * kb.y + qb.z * kb.z + qb.w * kb.w;
#pragma unroll
    for (int s = 1; s < 32; s <<= 1) d += __shfl_xor(d, s);
    if (c8 == 0) dots[row] = d;
}

// One wave stages a contiguous 4KB chunk (256 short8) via 4 global_load_lds
// width=16. LDS dest is wave-uniform base + lane*16 (HW rule).
__device__ __forceinline__ void stage_chunk(const short8* __restrict__ src_base,
                                            short8* lds_base, int lane) {
#pragma unroll
    for (int i = 0; i < 4; ++i) {
        const short8* g = src_base + i * 64 + lane;
        short8* l = lds_base + i * 64;
        __builtin_amdgcn_global_load_lds(
            (const __attribute__((address_space(1))) unsigned int*)g,
            (__attribute__((address_space(3))) unsigned int*)l,
            16, 0, 0);
    }
}

// Flash-LSE partials: grid (64, 16) = 1024 blocks, 3 resident/CU
// (VGPR ~150 @ cap 170; LDS 3x32KB = 96KB). Independent per-block barriers
// overlap: while one block drains its stage, two others compute.
// K tile (32 keys = 16KB) double-buffered; fragments lane-linear ->
// conflict-free ds_read_b128. Q fragments (qf[2][8] = 64 VGPR) in registers.
// C/D map: col=lane&15, row=(lane>>4)*4+reg [verified r2/r4/r6/r8/r11 pass].
__global__ __launch_bounds__(256, 3) void flash_lse_kernel(
        const short8* __restrict__ qbT,
        const short8* __restrict__ kbT,
        float* __restrict__ part_m,
        float* __restrict__ part_s) {
    __shared__ short8 smem[2][1024];   // 2 x 16KB

    const int mblk  = blockIdx.x;
    const int split = blockIdx.y;
    const int wid   = threadIdx.x >> 6;
    const int lane  = threadIdx.x & 63;
    const int l16   = lane & 15;
    const int lg    = lane >> 4;
    const int rt16  = mblk * 8 + wid * 2;   // first of this wave's two row-tiles

    // Hoist Q fragments: 16 coalesced 1KB loads, live for the whole kernel.
    short8 qf[2][8];
#pragma unroll
    for (int rt = 0; rt < 2; ++rt)
#pragma unroll
        for (int kk = 0; kk < 8; ++kk)
            qf[rt][kk] = qbT[(size_t)((rt16 + rt) * 8 + kk) * 64 + lane];

    float m_loc[2][4], s_loc[2][4];
#pragma unroll
    for (int rt = 0; rt < 2; ++rt)
#pragma unroll
        for (int j = 0; j < 4; ++j) { m_loc[rt][j] = -1e30f; s_loc[rt][j] = 0.f; }

    // split covers 32 col-tiles from split*32; iter covers 2 col-tiles
    // (32 keys = 1024 contiguous short8 = 16KB).
    const size_t tile_base0 = (size_t)(split * 32) * 512;

    // prologue: stage tile 0 into buf 0 (each of 4 waves stages 4KB)
    stage_chunk(kbT + tile_base0 + wid * 256, &smem[0][wid * 256], lane);
    __syncthreads();   // drains vmcnt -> tile 0 resident

    for (int it = 0; it < NIT; ++it) {
        const int cur = it & 1;
        if (it + 1 < NIT) {
            const size_t nbase = tile_base0 + (size_t)(it + 1) * 1024;
            stage_chunk(kbT + nbase + wid * 256, &smem[cur ^ 1][wid * 256], lane);
        }

        f32x4 acc[2][2];
#pragma unroll
        for (int rt = 0; rt < 2; ++rt)
#pragma unroll
            for (int ct = 0; ct < 2; ++ct)
                acc[rt][ct] = (f32x4){0.f, 0.f, 0.f, 0.f};

        const short8* sb = smem[cur];
#pragma unroll
        for (int kk = 0; kk < 8; ++kk) {
            short8 bf[2];
#pragma unroll
            for (int ct = 0; ct < 2; ++ct)
                bf[ct] = sb[ct * 512 + kk * 64 + lane];
#pragma unroll
            for (int rt = 0; rt < 2; ++rt)
#pragma unroll
                for (int ct = 0; ct < 2; ++ct)
                    acc[rt][ct] = __builtin_amdgcn_mfma_f32_16x16x32_bf16(
                        qf[rt][kk], bf[ct], acc[rt][ct], 0, 0, 0);
        }

        // online logsumexp update (base-2 domain), per-lane partial over cols
#pragma unroll
        for (int rt = 0; rt < 2; ++rt) {
#pragma unroll
            for (int j = 0; j < 4; ++j) {
                const float x0 = acc[rt][0][j], x1 = acc[rt][1][j];
                const float mo = m_loc[rt][j];
                const float mn = fmaxf(fmaxf(x0, x1), mo);
                float s = s_loc[rt][j] * EXP2R(mo - mn);
                s += EXP2R(x0 - mn) + EXP2R(x1 - mn);
                m_loc[rt][j] = mn;
                s_loc[rt][j] = s;
            }
        }

        __syncthreads();   // next tile landed (vmcnt drain) + all waves done with cur
    }

    // reduce (m,s) across the 16 lanes holding different columns of each row
#pragma unroll
    for (int rt = 0; rt < 2; ++rt) {
#pragma unroll
        for (int j = 0; j < 4; ++j) {
            float m = m_loc[rt][j], s = s_loc[rt][j];
#pragma unroll
            for (int d = 1; d < 16; d <<= 1) {
                const float mo = __shfl_xor(m, d);
                const float so = __shfl_xor(s, d);
                const float mn = fmaxf(m, mo);
                s = s * EXP2R(m - mn) + so * EXP2R(mo - mn);
                m = mn;
            }
            if (l16 == 0) {
                const int row = (rt16 + rt) * 16 + lg * 4 + j;
                part_m[split * MTOT + row] = m;
                part_s[split * MTOT + row] = s;
            }
        }
    }
}

// 16 lanes per row: merge the 16 split-partials + exact positive dot -> loss.
__global__ void combine_kernel(const float* __restrict__ dots,
                               const float* __restrict__ part_m,
                               const float* __restrict__ part_s,
                               float* __restrict__ out) {
    const int tid  = blockIdx.x * blockDim.x + threadIdx.x;
    const int row  = tid >> 4;
    const int l16  = tid & 15;
    float m = part_m[l16 * MTOT + row];
    float s = part_s[l16 * MTOT + row];
#pragma unroll
    for (int d = 1; d < 16; d <<= 1) {
        const float mo = __shfl_xor(m, d);
        const float so = __shfl_xor(s, d);
        const float mn = fmaxf(m, mo);
        s = s * EXP2R(m - mn) + so * EXP2R(mo - mn);
        m = mn;
    }
    if (l16 == 0) {
        out[row] = (m + __log2f(s)) * LN2 - INV_T_F * dots[row];
    }
}

extern "C" void kernel_launch(void* const* d_in, const int* in_sizes, int n_in,
                              void* d_out, int out_size, void* d_ws, size_t ws_size,
                              hipStream_t stream) {
    const float* q = (const float*)d_in[0];
    const float* k = (const float*)d_in[1];
    float* out = (float*)d_out;

    char* ws = (char*)d_ws;
    short8* qbT   = (short8*)ws;                                    // 4 MB
    short8* kbT   = (short8*)(ws + (size_t)NFRAG * 16);             // 4 MB
    float* part_m = (float*)(ws + (size_t)NFRAG * 32);              // 512 KB
    float* part_s = part_m + SPLITS * MTOT;                         // 512 KB
    float* dots   = part_s + SPLITS * MTOT;                         // 32 KB

    convert_kernel<<<NFRAG / 256, 256, 0, stream>>>(q, k, qbT, kbT, dots);
    dim3 grid(MTOT / BM, SPLITS);
    flash_lse_kernel<<<grid, 256, 0, stream>>>(qbT, kbT, part_m, part_s);
    combine_kernel<<<(MTOT * 16) / 256, 256, 0, stream>>>(dots, part_m, part_s, out);
}